// Round 3
// baseline (790.749 us; speedup 1.0000x reference)
//
#include <hip/hip_runtime.h>
#include <hip/hip_bf16.h>

typedef __hip_bfloat16 bf16;
typedef short short8 __attribute__((ext_vector_type(8)));
typedef float f32x4 __attribute__((ext_vector_type(4)));

#define NB 128
#define NPIX 196      // 14*14
#define NPAD 208      // 13*16
#define VP 224        // v4 row pitch (7*32 for PV k-steps), cols [208,224) zeroed
#define QROWS 208     // q/k rows allocated+written (pad rows zeroed)
#define NH 8
#define KD 32
#define DHEAD 128
#define DH 1024
#define DIM 384
#define SCALE 0.17677669529663687f

__device__ __forceinline__ float b2f(bf16 v) { return __bfloat162float(v); }
__device__ __forceinline__ bf16 f2b(float f) { return __float2bfloat16(f); }

// ---------- fp32 -> bf16 weight conversion ----------
__global__ __launch_bounds__(256) void k_cvt(const float* __restrict__ src,
                                             bf16* __restrict__ dst, int n) {
  int i = blockIdx.x * 256 + threadIdx.x;
  if (i < n) dst[i] = f2b(src[i]);
}

// ---------- transpose x (B,384,196) fp32 -> XT (B,208,384) bf16, rows >=196 zeroed ----------
__global__ __launch_bounds__(256) void k_xt(const float* __restrict__ x,
                                            bf16* __restrict__ XT) {
  __shared__ bf16 tile[32][33];
  int ct = blockIdx.x, nt = blockIdx.y, b = blockIdx.z;
  int c0 = ct * 32, n0 = nt * 32;
  int tc = threadIdx.x >> 5, tn = threadIdx.x & 31;
#pragma unroll
  for (int r = 0; r < 4; ++r) {
    int c = tc + r * 8;
    int n = n0 + tn;
    float v = 0.f;
    if (n < NPIX) v = x[((size_t)b * DIM + c0 + c) * NPIX + n];
    tile[c][tn] = f2b(v);
  }
  __syncthreads();
#pragma unroll
  for (int r = 0; r < 4; ++r) {
    int n = n0 + tc + r * 8;
    if (n < NPAD) XT[((size_t)b * NPAD + n) * DIM + c0 + tn] = tile[tn][tc + r * 8];
  }
}

// ---------- fused QKV projection GEMM (direct-global MFMA fragments) ----------
__global__ __launch_bounds__(256) void k_qkv(
    const bf16* __restrict__ XT,
    const bf16* __restrict__ qw, const bf16* __restrict__ kw, const bf16* __restrict__ vw,
    const float* __restrict__ qb, const float* __restrict__ kb, const float* __restrict__ vb,
    const float* __restrict__ qs, const float* __restrict__ ks, const float* __restrict__ vs,
    const float* __restrict__ qt, const float* __restrict__ kt, const float* __restrict__ vt,
    bf16* __restrict__ qf, bf16* __restrict__ kf, bf16* __restrict__ v4) {
  int mt = blockIdx.x, b = blockIdx.y;
  int m0 = mt * 64;
  int wave = threadIdx.x >> 6, lane = threadIdx.x & 63;
  const bf16* wp;
  const float *bp, *sp, *tp;
  int seg, mo;
  if (m0 < 256)      { wp = qw; bp = qb; sp = qs; tp = qt; seg = 0; mo = m0; }
  else if (m0 < 512) { wp = kw; bp = kb; sp = ks; tp = kt; seg = 1; mo = m0 - 256; }
  else               { wp = vw; bp = vb; sp = vs; tp = vt; seg = 2; mo = m0 - 512; }
  const bf16* ap  = wp + (size_t)(mo + wave * 16 + (lane & 15)) * DIM + ((lane >> 4) << 3);
  const bf16* bp0 = XT + (size_t)b * NPAD * DIM + (size_t)(lane & 15) * DIM + ((lane >> 4) << 3);
  f32x4 acc[13];
#pragma unroll
  for (int t = 0; t < 13; ++t)
#pragma unroll
    for (int r = 0; r < 4; ++r) acc[t][r] = 0.f;
  for (int k0 = 0; k0 < DIM; k0 += 32) {
    short8 a = *(const short8*)(ap + k0);
#pragma unroll
    for (int t = 0; t < 13; ++t) {
      short8 bb = *(const short8*)(bp0 + (size_t)t * 16 * DIM + k0);
      acc[t] = __builtin_amdgcn_mfma_f32_16x16x32_bf16(a, bb, acc[t], 0, 0, 0);
    }
  }
#pragma unroll
  for (int r = 0; r < 4; ++r) {
    int ms = mo + wave * 16 + ((lane >> 4) << 2) + r;  // segment-local out channel
    float bi = bp[ms], sc = sp[ms], tt = tp[ms];
#pragma unroll
    for (int t = 0; t < 13; ++t) {
      int n = t * 16 + (lane & 15);
      float y = (acc[t][r] + bi) * sc + tt;
      if (seg == 2) {
        v4[((size_t)b * DH + ms) * VP + n] = f2b(n < NPIX ? y : 0.f);
      } else {
        int h = ms >> 5, d = ms & 31;
        bf16* dst = (seg == 0) ? qf : kf;
        dst[(((size_t)b * NH + h) * QROWS + n) * KD + d] = f2b(n < NPIX ? y : 0.f);
      }
    }
    if (seg == 2)  // zero v4 cols [208,224)
      v4[((size_t)b * DH + ms) * VP + 208 + (lane & 15)] = f2b(0.f);
  }
}

// ---------- depthwise 3x3 + BN ----------
__global__ __launch_bounds__(256) void k_dw(
    const bf16* __restrict__ v4, const float* __restrict__ lvw,
    const float* __restrict__ lvb, const float* __restrict__ lvs,
    const float* __restrict__ lvt, bf16* __restrict__ vl) {
  int blk = blockIdx.x;
  int b = blk >> 8, cg = blk & 255;
  int lc = threadIdx.x >> 6, px = threadIdx.x & 63;
  int ch = cg * 4 + lc;
  const bf16* src = v4 + ((size_t)b * DH + ch) * VP;
  float w[9];
#pragma unroll
  for (int i = 0; i < 9; ++i) w[i] = lvw[ch * 9 + i];
  float bb = lvb[ch], ss = lvs[ch], tt = lvt[ch];
  bf16* dst = vl + ((size_t)b * DH + ch) * NPIX;
  for (int p = px; p < NPIX; p += 64) {
    int ri = p / 14, ci = p - ri * 14;
    float s = 0.f;
#pragma unroll
    for (int dy = -1; dy <= 1; ++dy)
#pragma unroll
      for (int dx = -1; dx <= 1; ++dx) {
        int rr = ri + dy, cc = ci + dx;
        if (rr >= 0 && rr < 14 && cc >= 0 && cc < 14)
          s += w[(dy + 1) * 3 + dx + 1] * b2f(src[rr * 14 + cc]);
      }
    dst[p] = f2b((s + bb) * ss + tt);
  }
}

// ---------- per-channel column sums of v (for the th2b term) ----------
__global__ __launch_bounds__(256) void k_vcs(const bf16* __restrict__ v4,
                                             float* __restrict__ vcs) {
  int b = blockIdx.x, g = blockIdx.y;
  int ch = g * 64 + (threadIdx.x >> 2);
  int part = threadIdx.x & 3;
  const bf16* src = v4 + ((size_t)b * DH + ch) * VP + part * 49;
  float s = 0.f;
  for (int j = 0; j < 49; ++j) s += b2f(src[j]);
  s += __shfl_xor(s, 1);
  s += __shfl_xor(s, 2);
  if (part == 0) vcs[b * DH + ch] = s;
}

// ---------- attention ----------
// S: bf16 [8 heads][16 rows][224 cols], row rotate-swizzled. 57344 B static LDS.
#define SROW 448  // bytes per S row
__device__ __forceinline__ int saddr(int g, int i, int j) {
  int r = j * 2 + ((i & 7) << 4);
  if (r >= SROW) r -= SROW;
  return (g * 16 + i) * SROW + r;
}

__global__ __launch_bounds__(512, 2) void k_att(
    const bf16* __restrict__ qf, const bf16* __restrict__ kf,
    const bf16* __restrict__ v4, const bf16* __restrict__ vl,
    const float* __restrict__ vcs,
    const float* __restrict__ th1w, const float* __restrict__ th1b,
    const float* __restrict__ th2w, const float* __restrict__ th2b,
    const float* __restrict__ ab, bf16* __restrict__ OT) {
  __shared__ __align__(16) char smem[NH * 16 * SROW];  // 57344 B
  __shared__ float ab2[NH * NPIX];                     // 6272 B
  __shared__ float c1[64];
  __shared__ float c2[64];
  int qt = blockIdx.x, b = blockIdx.y;
  int i0 = qt * 16;
  int tid = threadIdx.x;
  int wave = tid >> 6, lane = tid & 63;
  int il = lane & 15, kh = lane >> 4;

  if (tid < 64) {
    c1[tid] = th1w[tid] * SCALE;
    c2[tid] = th2w[tid];
  }
  for (int pos = tid; pos < NH * NPIX; pos += 512) {
    int g = pos / NPIX, off = pos - g * NPIX;
    float s = th1b[g];
#pragma unroll
    for (int h = 0; h < 8; ++h)
      s += th1w[g * 8 + h] * ab[h * NPIX + off];
    ab2[pos] = s;
  }
  // ---- QK^T, head = wave; 16 q-rows x 208 k-rows, raw qk -> S (bf16) ----
  {
    const bf16* qp = qf + ((size_t)b * NH + wave) * QROWS * KD;
    const bf16* kp = kf + ((size_t)b * NH + wave) * QROWS * KD;
    short8 a = *(const short8*)(qp + (i0 + il) * KD + kh * 8);
    for (int jt = 0; jt < 13; ++jt) {
      short8 bb = *(const short8*)(kp + (jt * 16 + il) * KD + kh * 8);
      f32x4 acc = {0.f, 0.f, 0.f, 0.f};
      acc = __builtin_amdgcn_mfma_f32_16x16x32_bf16(a, bb, acc, 0, 0, 0);
      int j = jt * 16 + il;
#pragma unroll
      for (int r = 0; r < 4; ++r)
        *(bf16*)(smem + saddr(wave, kh * 4 + r, j)) = f2b(acc[r]);
    }
  }
  __syncthreads();
  // ---- pass A: talking-head-1 mix (with SCALE) + relative-position bias ----
  for (int pos = tid; pos < 16 * NPIX; pos += 512) {
    int i = pos / NPIX, j = pos - i * NPIX;
    float sv[8];
#pragma unroll
    for (int h = 0; h < 8; ++h) sv[h] = b2f(*(const bf16*)(smem + saddr(h, i, j)));
    int ia = i0 + i; if (ia > 195) ia = 195;
    int ri = ia / 14, ci = ia - ri * 14;
    int rj = j / 14, cj = j - rj * 14;
    int dr = ri > rj ? ri - rj : rj - ri;
    int dc = ci > cj ? ci - cj : cj - ci;
    int off = dr * 14 + dc;
    float outv[8];
#pragma unroll
    for (int g = 0; g < 8; ++g) {
      float s = ab2[g * NPIX + off];
#pragma unroll
      for (int h = 0; h < 8; ++h) s += c1[g * 8 + h] * sv[h];
      outv[g] = s;
    }
#pragma unroll
    for (int g = 0; g < 8; ++g)
      *(bf16*)(smem + saddr(g, i, j)) = f2b(outv[g]);
  }
  __syncthreads();
  // ---- pass B: softmax over j (4 threads per (g,i) row), zero pad cols ----
  {
    int row = tid >> 2, part = tid & 3;  // 128 rows = 8 heads x 16
    int g = row >> 4, i = row & 15;
    int jb = part * 49, je = jb + 49;
    float m = -1e30f;
    for (int j = jb; j < je; ++j)
      m = fmaxf(m, b2f(*(const bf16*)(smem + saddr(g, i, j))));
    m = fmaxf(m, __shfl_xor(m, 1));
    m = fmaxf(m, __shfl_xor(m, 2));
    float s = 0.f;
    for (int j = jb; j < je; ++j)
      s += __expf(b2f(*(const bf16*)(smem + saddr(g, i, j))) - m);
    s += __shfl_xor(s, 1);
    s += __shfl_xor(s, 2);
    float inv = 1.f / s;
    for (int j = jb; j < je; ++j) {
      bf16* p = (bf16*)(smem + saddr(g, i, j));
      *p = f2b(__expf(b2f(*p) - m) * inv);
    }
    if (part == 3)
      for (int j = NPIX; j < VP; ++j)
        *(bf16*)(smem + saddr(g, i, j)) = f2b(0.f);
  }
  __syncthreads();
  // ---- pass C: talking-head-2 mix ----
  for (int pos = tid; pos < 16 * NPIX; pos += 512) {
    int i = pos / NPIX, j = pos - i * NPIX;
    float pv[8];
#pragma unroll
    for (int g = 0; g < 8; ++g) pv[g] = b2f(*(const bf16*)(smem + saddr(g, i, j)));
#pragma unroll
    for (int g2 = 0; g2 < 8; ++g2) {
      float s = 0.f;
#pragma unroll
      for (int g = 0; g < 8; ++g) s += c2[g2 * 8 + g] * pv[g];
      *(bf16*)(smem + saddr(g2, i, j)) = f2b(s);
    }
  }
  __syncthreads();
  // ---- PV: O_g = P_g @ V_g^T, +th2b*colsum(v) +vl, relu, store transposed ----
  {
    int g = wave;
    f32x4 oacc[8];
#pragma unroll
    for (int dt = 0; dt < 8; ++dt)
#pragma unroll
      for (int r = 0; r < 4; ++r) oacc[dt][r] = 0.f;
    const bf16* vbase = v4 + ((size_t)b * DH + g * DHEAD) * VP;
    for (int ks = 0; ks < 7; ++ks) {
      short8 pa = *(const short8*)(smem + saddr(g, il, ks * 32 + kh * 8));
#pragma unroll
      for (int dt = 0; dt < 8; ++dt) {
        short8 bv = *(const short8*)(vbase + (size_t)(dt * 16 + il) * VP + ks * 32 + kh * 8);
        oacc[dt] = __builtin_amdgcn_mfma_f32_16x16x32_bf16(pa, bv, oacc[dt], 0, 0, 0);
      }
    }
    float t2b = th2b[g];
#pragma unroll
    for (int dt = 0; dt < 8; ++dt) {
      int ch = g * DHEAD + dt * 16 + il;
      float csv = vcs[b * DH + ch] * t2b;
#pragma unroll
      for (int r = 0; r < 4; ++r) {
        int n = i0 + kh * 4 + r;
        if (n < NPIX) {
          float val = oacc[dt][r] + csv + b2f(vl[((size_t)b * DH + ch) * NPIX + n]);
          OT[((size_t)b * NPAD + n) * DH + ch] = f2b(fmaxf(val, 0.f));
        } else {
          OT[((size_t)b * NPAD + n) * DH + ch] = f2b(0.f);
        }
      }
    }
  }
}

// ---------- final projection GEMM (fp32 out) ----------
__global__ __launch_bounds__(256) void k_p(
    const bf16* __restrict__ OT, const bf16* __restrict__ pw,
    const float* __restrict__ pb, const float* __restrict__ ps,
    const float* __restrict__ pt, float* __restrict__ out) {
  int mt = blockIdx.x, b = blockIdx.y;
  int m0 = mt * 64;
  int wave = threadIdx.x >> 6, lane = threadIdx.x & 63;
  const bf16* ap  = pw + (size_t)(m0 + wave * 16 + (lane & 15)) * DH + ((lane >> 4) << 3);
  const bf16* bp0 = OT + (size_t)b * NPAD * DH + (size_t)(lane & 15) * DH + ((lane >> 4) << 3);
  f32x4 acc[13];
#pragma unroll
  for (int t = 0; t < 13; ++t)
#pragma unroll
    for (int r = 0; r < 4; ++r) acc[t][r] = 0.f;
  for (int k0 = 0; k0 < DH; k0 += 32) {
    short8 a = *(const short8*)(ap + k0);
#pragma unroll
    for (int t = 0; t < 13; ++t) {
      short8 bb = *(const short8*)(bp0 + (size_t)t * 16 * DH + k0);
      acc[t] = __builtin_amdgcn_mfma_f32_16x16x32_bf16(a, bb, acc[t], 0, 0, 0);
    }
  }
#pragma unroll
  for (int r = 0; r < 4; ++r) {
    int m = m0 + wave * 16 + ((lane >> 4) << 2) + r;
    float bi = pb[m], sc = ps[m], tt = pt[m];
#pragma unroll
    for (int t = 0; t < 13; ++t) {
      int n = t * 16 + (lane & 15);
      if (n < NPIX)
        out[((size_t)b * DIM + m) * NPIX + n] = (acc[t][r] + bi) * sc + tt;
    }
  }
}

extern "C" void kernel_launch(void* const* d_in, const int* in_sizes, int n_in,
                              void* d_out, int out_size, void* d_ws, size_t ws_size,
                              hipStream_t stream) {
  const float* x    = (const float*)d_in[0];
  const float* qw   = (const float*)d_in[1];
  const float* qb   = (const float*)d_in[2];
  const float* q_s  = (const float*)d_in[3];
  const float* q_t  = (const float*)d_in[4];
  const float* kw   = (const float*)d_in[5];
  const float* kb   = (const float*)d_in[6];
  const float* k_s  = (const float*)d_in[7];
  const float* k_t  = (const float*)d_in[8];
  const float* vw   = (const float*)d_in[9];
  const float* vb   = (const float*)d_in[10];
  const float* v_s  = (const float*)d_in[11];
  const float* v_t  = (const float*)d_in[12];
  const float* lvw  = (const float*)d_in[13];
  const float* lvb  = (const float*)d_in[14];
  const float* lv_s = (const float*)d_in[15];
  const float* lv_t = (const float*)d_in[16];
  const float* th1w = (const float*)d_in[17];
  const float* th1b = (const float*)d_in[18];
  const float* th2w = (const float*)d_in[19];
  const float* th2b = (const float*)d_in[20];
  const float* ab   = (const float*)d_in[21];
  const float* pw   = (const float*)d_in[22];
  const float* pb   = (const float*)d_in[23];
  const float* p_s  = (const float*)d_in[24];
  const float* p_t  = (const float*)d_in[25];

  char* ws = (char*)d_ws;
  size_t off = 0;
  auto alloc = [&](size_t bytes) {
    char* p = ws + off;
    off += (bytes + 255) & ~(size_t)255;
    return p;
  };
  // region0: XT (B,208,384 bf16, 20.4MB) aliased with OT (B,208,1024 bf16, 54.5MB)
  char* region0 = alloc((size_t)NB * NPAD * DH * 2);
  bf16* XT  = (bf16*)region0;
  bf16* OT  = (bf16*)region0;
  bf16* qfb = (bf16*)alloc((size_t)NB * NH * QROWS * KD * 2);
  bf16* kfb = (bf16*)alloc((size_t)NB * NH * QROWS * KD * 2);
  bf16* v4  = (bf16*)alloc((size_t)NB * DH * VP * 2);
  bf16* vlb = (bf16*)alloc((size_t)NB * DH * NPIX * 2);
  float* vcs = (float*)alloc((size_t)NB * DH * 4);
  bf16* wq = (bf16*)alloc((size_t)256 * DIM * 2);
  bf16* wk = (bf16*)alloc((size_t)256 * DIM * 2);
  bf16* wv = (bf16*)alloc((size_t)DH * DIM * 2);
  bf16* wp = (bf16*)alloc((size_t)DIM * DH * 2);
  (void)ws_size; (void)in_sizes; (void)n_in; (void)out_size;

  k_cvt<<<dim3((256 * DIM + 255) / 256), 256, 0, stream>>>(qw, wq, 256 * DIM);
  k_cvt<<<dim3((256 * DIM + 255) / 256), 256, 0, stream>>>(kw, wk, 256 * DIM);
  k_cvt<<<dim3((DH * DIM + 255) / 256), 256, 0, stream>>>(vw, wv, DH * DIM);
  k_cvt<<<dim3((DIM * DH + 255) / 256), 256, 0, stream>>>(pw, wp, DIM * DH);
  k_xt<<<dim3(12, 7, NB), 256, 0, stream>>>(x, XT);
  k_qkv<<<dim3(24, NB), 256, 0, stream>>>(XT, wq, wk, wv, qb, kb, vb,
                                          q_s, k_s, v_s, q_t, k_t, v_t,
                                          qfb, kfb, v4);
  k_dw<<<dim3(NB * 256), 256, 0, stream>>>(v4, lvw, lvb, lv_s, lv_t, vlb);
  k_vcs<<<dim3(NB, 16), 256, 0, stream>>>(v4, vcs);
  k_att<<<dim3(13, NB), 512, 0, stream>>>(qfb, kfb, v4, vlb, vcs,
                                          th1w, th1b, th2w, th2b, ab, OT);
  k_p<<<dim3(6, NB), 256, 0, stream>>>(OT, wp, pb, p_s, p_t, (float*)d_out);
}

// Round 4
// 498.824 us; speedup vs baseline: 1.5852x; 1.5852x over previous
//
#include <hip/hip_runtime.h>
#include <hip/hip_bf16.h>
#include <stdint.h>

typedef __hip_bfloat16 bf16;
typedef short short8 __attribute__((ext_vector_type(8)));
typedef float f32x4 __attribute__((ext_vector_type(4)));

#define NB 128
#define NPIX 196      // 14*14
#define NPAD 208      // 13*16
#define VP 224        // v4 row pitch (7*32 for PV k-steps), cols [208,224) zeroed
#define QROWS 208     // q/k rows allocated+written (pad rows zeroed)
#define NH 8
#define KD 32
#define DHEAD 128
#define DH 1024
#define DIM 384
#define NROWS (NB * NPAD)   // 26624 fused pixel-rows
#define SCALE 0.17677669529663687f

__device__ __forceinline__ float b2f(bf16 v) { return __bfloat162float(v); }
__device__ __forceinline__ bf16 f2b(float f) { return __float2bfloat16(f); }

// CK-style global->LDS 16B async copy
__device__ __forceinline__ void gll16(const void* g, void* l) {
  auto gp = reinterpret_cast<const uint32_t __attribute__((address_space(1)))*>(
      reinterpret_cast<uintptr_t>(g));
  auto lp = reinterpret_cast<uint32_t __attribute__((address_space(3)))*>(
      reinterpret_cast<uintptr_t>(l));
  __builtin_amdgcn_global_load_lds(gp, lp, 16, 0, 0);
}

// ---------- fp32 -> bf16 weight conversion ----------
__global__ __launch_bounds__(256) void k_cvt(const float* __restrict__ src,
                                             bf16* __restrict__ dst, int n) {
  int i = blockIdx.x * 256 + threadIdx.x;
  if (i < n) dst[i] = f2b(src[i]);
}

// ---------- transpose x (B,384,196) fp32 -> XT (B,208,384) bf16, rows >=196 zeroed ----------
__global__ __launch_bounds__(256) void k_xt(const float* __restrict__ x,
                                            bf16* __restrict__ XT) {
  __shared__ bf16 tile[32][33];
  int ct = blockIdx.x, nt = blockIdx.y, b = blockIdx.z;
  int c0 = ct * 32, n0 = nt * 32;
  int tc = threadIdx.x >> 5, tn = threadIdx.x & 31;
#pragma unroll
  for (int r = 0; r < 4; ++r) {
    int c = tc + r * 8;
    int n = n0 + tn;
    float v = 0.f;
    if (n < NPIX) v = x[((size_t)b * DIM + c0 + c) * NPIX + n];
    tile[c][tn] = f2b(v);
  }
  __syncthreads();
#pragma unroll
  for (int r = 0; r < 4; ++r) {
    int n = n0 + tc + r * 8;
    if (n < NPAD) XT[((size_t)b * NPAD + n) * DIM + c0 + tn] = tile[tn][tc + r * 8];
  }
}

// ---------- fused QKV projection: LDS-staged 128x128 tile GEMM ----------
// A = Wf [1536][384] bf16, B = XT [26624][384] bf16.
__global__ __launch_bounds__(256, 2) void k_qkv2(
    const bf16* __restrict__ Wf, const bf16* __restrict__ XT,
    const float* __restrict__ qb, const float* __restrict__ qs, const float* __restrict__ qt,
    const float* __restrict__ kb, const float* __restrict__ ks, const float* __restrict__ kt,
    const float* __restrict__ vb, const float* __restrict__ vs, const float* __restrict__ vt,
    bf16* __restrict__ qf, bf16* __restrict__ kf, bf16* __restrict__ v4) {
  __shared__ __align__(16) char lds[2][32768];  // [buf][A 16KB | B 16KB]
  const int NWG = 12 * 208;  // 2496, %8==0
  int id = blockIdx.x;
  int id2 = (id & 7) * (NWG >> 3) + (id >> 3);  // XCD-contiguous
  int mt = id2 % 12, nt = id2 / 12;
  int m0 = mt * 128, n0 = nt * 128;
  int tid = threadIdx.x, lane = tid & 63;
  int wv = tid >> 6, wm = wv >> 1, wn = wv & 1;

  f32x4 acc[4][4];
#pragma unroll
  for (int mi = 0; mi < 4; ++mi)
#pragma unroll
    for (int ni = 0; ni < 4; ++ni)
#pragma unroll
      for (int r = 0; r < 4; ++r) acc[mi][ni][r] = 0.f;

  auto stage = [&](int buf, int t) {
    int k0 = t * 64;
#pragma unroll
    for (int j = 0; j < 4; ++j) {
      int gi = tid + j * 256;
      int row = gi >> 3, g = gi & 7;
      int sk = k0 + ((g ^ (row & 7)) << 3);
      gll16(Wf + (size_t)(m0 + row) * DIM + sk, &lds[buf][gi * 16]);
      gll16(XT + (size_t)(n0 + row) * DIM + sk, &lds[buf][16384 + gi * 16]);
    }
  };
  auto compute = [&](int buf) {
    const char* Ab = lds[buf];
    const char* Bb = lds[buf] + 16384;
    int kq = lane >> 4, il = lane & 15;
#pragma unroll
    for (int ksb = 0; ksb < 2; ++ksb) {
      int G = ksb * 4 + kq;
      short8 af[4], bfr[4];
#pragma unroll
      for (int mi = 0; mi < 4; ++mi) {
        int row = wm * 64 + mi * 16 + il;
        af[mi] = *(const short8*)(Ab + row * 128 + ((G ^ (row & 7)) << 4));
      }
#pragma unroll
      for (int ni = 0; ni < 4; ++ni) {
        int row = wn * 64 + ni * 16 + il;
        bfr[ni] = *(const short8*)(Bb + row * 128 + ((G ^ (row & 7)) << 4));
      }
#pragma unroll
      for (int mi = 0; mi < 4; ++mi)
#pragma unroll
        for (int ni = 0; ni < 4; ++ni)
          acc[mi][ni] = __builtin_amdgcn_mfma_f32_16x16x32_bf16(af[mi], bfr[ni], acc[mi][ni], 0, 0, 0);
    }
  };

  stage(0, 0);
  __syncthreads();
  for (int t = 0; t < 6; ++t) {
    if (t < 5) stage((t + 1) & 1, t + 1);
    compute(t & 1);
    __syncthreads();
  }

  int cq = lane >> 4, cn = lane & 15;
#pragma unroll
  for (int mi = 0; mi < 4; ++mi) {
    int mbase = m0 + wm * 64 + mi * 16;
    const float *bp, *sp, *tp;
    int segbase, segid;
    if (mbase < 256)      { bp = qb; sp = qs; tp = qt; segbase = 0;   segid = 0; }
    else if (mbase < 512) { bp = kb; sp = ks; tp = kt; segbase = 256; segid = 1; }
    else                  { bp = vb; sp = vs; tp = vt; segbase = 512; segid = 2; }
#pragma unroll
    for (int r = 0; r < 4; ++r) {
      int ms = mbase - segbase + cq * 4 + r;
      float bi = bp[ms], sc = sp[ms], tt = tp[ms];
#pragma unroll
      for (int ni = 0; ni < 4; ++ni) {
        int n = n0 + wn * 64 + ni * 16 + cn;
        int b = n / NPAD;
        int nn = n - b * NPAD;
        float y = (acc[mi][ni][r] + bi) * sc + tt;
        y = (nn < NPIX) ? y : 0.f;
        if (segid == 2) {
          v4[((size_t)b * DH + ms) * VP + nn] = f2b(y);
        } else {
          bf16* dst = segid ? kf : qf;
          dst[(((size_t)b * NH + (ms >> 5)) * QROWS + nn) * KD + (ms & 31)] = f2b(y);
        }
      }
    }
  }
}

// ---------- zero v4 pad cols [208,224) ----------
__global__ __launch_bounds__(256) void k_vpad(bf16* __restrict__ v4) {
  int i = blockIdx.x * 256 + threadIdx.x;
  int tot = NB * DH * 16;
  if (i < tot) {
    int row = i >> 4, c = i & 15;
    v4[(size_t)row * VP + 208 + c] = f2b(0.f);
  }
}

// ---------- final projection: LDS-staged 128x128 tile GEMM, fp32 out ----------
// A = Pw [384][1024] bf16, B = OT [26624][1024] bf16.
__global__ __launch_bounds__(256, 2) void k_p2(
    const bf16* __restrict__ Pw, const bf16* __restrict__ OT,
    const float* __restrict__ pb, const float* __restrict__ ps, const float* __restrict__ pt,
    float* __restrict__ out) {
  __shared__ __align__(16) char lds[2][32768];
  const int NWG = 3 * 208;  // 624, %8==0
  int id = blockIdx.x;
  int id2 = (id & 7) * (NWG >> 3) + (id >> 3);
  int mt = id2 % 3, nt = id2 / 3;
  int m0 = mt * 128, n0 = nt * 128;
  int tid = threadIdx.x, lane = tid & 63;
  int wv = tid >> 6, wm = wv >> 1, wn = wv & 1;

  f32x4 acc[4][4];
#pragma unroll
  for (int mi = 0; mi < 4; ++mi)
#pragma unroll
    for (int ni = 0; ni < 4; ++ni)
#pragma unroll
      for (int r = 0; r < 4; ++r) acc[mi][ni][r] = 0.f;

  auto stage = [&](int buf, int t) {
    int k0 = t * 64;
#pragma unroll
    for (int j = 0; j < 4; ++j) {
      int gi = tid + j * 256;
      int row = gi >> 3, g = gi & 7;
      int sk = k0 + ((g ^ (row & 7)) << 3);
      gll16(Pw + (size_t)(m0 + row) * DH + sk, &lds[buf][gi * 16]);
      gll16(OT + (size_t)(n0 + row) * DH + sk, &lds[buf][16384 + gi * 16]);
    }
  };
  auto compute = [&](int buf) {
    const char* Ab = lds[buf];
    const char* Bb = lds[buf] + 16384;
    int kq = lane >> 4, il = lane & 15;
#pragma unroll
    for (int ksb = 0; ksb < 2; ++ksb) {
      int G = ksb * 4 + kq;
      short8 af[4], bfr[4];
#pragma unroll
      for (int mi = 0; mi < 4; ++mi) {
        int row = wm * 64 + mi * 16 + il;
        af[mi] = *(const short8*)(Ab + row * 128 + ((G ^ (row & 7)) << 4));
      }
#pragma unroll
      for (int ni = 0; ni < 4; ++ni) {
        int row = wn * 64 + ni * 16 + il;
        bfr[ni] = *(const short8*)(Bb + row * 128 + ((G ^ (row & 7)) << 4));
      }
#pragma unroll
      for (int mi = 0; mi < 4; ++mi)
#pragma unroll
        for (int ni = 0; ni < 4; ++ni)
          acc[mi][ni] = __builtin_amdgcn_mfma_f32_16x16x32_bf16(af[mi], bfr[ni], acc[mi][ni], 0, 0, 0);
    }
  };

  stage(0, 0);
  __syncthreads();
  for (int t = 0; t < 16; ++t) {
    if (t < 15) stage((t + 1) & 1, t + 1);
    compute(t & 1);
    __syncthreads();
  }

  int cq = lane >> 4, cn = lane & 15;
#pragma unroll
  for (int mi = 0; mi < 4; ++mi) {
#pragma unroll
    for (int r = 0; r < 4; ++r) {
      int m = m0 + wm * 64 + mi * 16 + cq * 4 + r;
      float bi = pb[m], sc = ps[m], tt = pt[m];
#pragma unroll
      for (int ni = 0; ni < 4; ++ni) {
        int n = n0 + wn * 64 + ni * 16 + cn;
        int b = n / NPAD;
        int nn = n - b * NPAD;
        if (nn < NPIX)
          out[((size_t)b * DIM + m) * NPIX + nn] = (acc[mi][ni][r] + bi) * sc + tt;
      }
    }
  }
}

// ---------- depthwise 3x3 + BN ----------
__global__ __launch_bounds__(256) void k_dw(
    const bf16* __restrict__ v4, const float* __restrict__ lvw,
    const float* __restrict__ lvb, const float* __restrict__ lvs,
    const float* __restrict__ lvt, bf16* __restrict__ vl) {
  int blk = blockIdx.x;
  int b = blk >> 8, cg = blk & 255;
  int lc = threadIdx.x >> 6, px = threadIdx.x & 63;
  int ch = cg * 4 + lc;
  const bf16* src = v4 + ((size_t)b * DH + ch) * VP;
  float w[9];
#pragma unroll
  for (int i = 0; i < 9; ++i) w[i] = lvw[ch * 9 + i];
  float bb = lvb[ch], ss = lvs[ch], tt = lvt[ch];
  bf16* dst = vl + ((size_t)b * DH + ch) * NPIX;
  for (int p = px; p < NPIX; p += 64) {
    int ri = p / 14, ci = p - ri * 14;
    float s = 0.f;
#pragma unroll
    for (int dy = -1; dy <= 1; ++dy)
#pragma unroll
      for (int dx = -1; dx <= 1; ++dx) {
        int rr = ri + dy, cc = ci + dx;
        if (rr >= 0 && rr < 14 && cc >= 0 && cc < 14)
          s += w[(dy + 1) * 3 + dx + 1] * b2f(src[rr * 14 + cc]);
      }
    dst[p] = f2b((s + bb) * ss + tt);
  }
}

// ---------- per-channel column sums of v (for the th2b term) ----------
__global__ __launch_bounds__(256) void k_vcs(const bf16* __restrict__ v4,
                                             float* __restrict__ vcs) {
  int b = blockIdx.x, g = blockIdx.y;
  int ch = g * 64 + (threadIdx.x >> 2);
  int part = threadIdx.x & 3;
  const bf16* src = v4 + ((size_t)b * DH + ch) * VP + part * 49;
  float s = 0.f;
  for (int j = 0; j < 49; ++j) s += b2f(src[j]);
  s += __shfl_xor(s, 1);
  s += __shfl_xor(s, 2);
  if (part == 0) vcs[b * DH + ch] = s;
}

// ---------- attention ----------
// S: bf16 [8 heads][16 rows][224 cols], row rotate-swizzled. 57344 B static LDS.
#define SROW 448  // bytes per S row
__device__ __forceinline__ int saddr(int g, int i, int j) {
  int r = j * 2 + ((i & 7) << 4);
  if (r >= SROW) r -= SROW;
  return (g * 16 + i) * SROW + r;
}

__global__ __launch_bounds__(512, 2) void k_att(
    const bf16* __restrict__ qf, const bf16* __restrict__ kf,
    const bf16* __restrict__ v4, const bf16* __restrict__ vl,
    const float* __restrict__ vcs,
    const float* __restrict__ th1w, const float* __restrict__ th1b,
    const float* __restrict__ th2w, const float* __restrict__ th2b,
    const float* __restrict__ ab, bf16* __restrict__ OT) {
  __shared__ __align__(16) char smem[NH * 16 * SROW];  // 57344 B
  __shared__ float ab2[NH * NPIX];                     // 6272 B
  __shared__ float c1[64];
  __shared__ float c2[64];
  int qt = blockIdx.x, b = blockIdx.y;
  int i0 = qt * 16;
  int tid = threadIdx.x;
  int wave = tid >> 6, lane = tid & 63;
  int il = lane & 15, kh = lane >> 4;

  if (tid < 64) {
    c1[tid] = th1w[tid] * SCALE;
    c2[tid] = th2w[tid];
  }
  for (int pos = tid; pos < NH * NPIX; pos += 512) {
    int g = pos / NPIX, off = pos - g * NPIX;
    float s = th1b[g];
#pragma unroll
    for (int h = 0; h < 8; ++h)
      s += th1w[g * 8 + h] * ab[h * NPIX + off];
    ab2[pos] = s;
  }
  // ---- QK^T, head = wave; 16 q-rows x 208 k-rows, raw qk -> S (bf16) ----
  {
    const bf16* qp = qf + ((size_t)b * NH + wave) * QROWS * KD;
    const bf16* kp = kf + ((size_t)b * NH + wave) * QROWS * KD;
    short8 a = *(const short8*)(qp + (i0 + il) * KD + kh * 8);
    for (int jt = 0; jt < 13; ++jt) {
      short8 bb = *(const short8*)(kp + (jt * 16 + il) * KD + kh * 8);
      f32x4 acc = {0.f, 0.f, 0.f, 0.f};
      acc = __builtin_amdgcn_mfma_f32_16x16x32_bf16(a, bb, acc, 0, 0, 0);
      int j = jt * 16 + il;
#pragma unroll
      for (int r = 0; r < 4; ++r)
        *(bf16*)(smem + saddr(wave, kh * 4 + r, j)) = f2b(acc[r]);
    }
  }
  __syncthreads();
  // ---- pass A: talking-head-1 mix (with SCALE) + relative-position bias ----
  for (int pos = tid; pos < 16 * NPIX; pos += 512) {
    int i = pos / NPIX, j = pos - i * NPIX;
    float sv[8];
#pragma unroll
    for (int h = 0; h < 8; ++h) sv[h] = b2f(*(const bf16*)(smem + saddr(h, i, j)));
    int ia = i0 + i; if (ia > 195) ia = 195;
    int ri = ia / 14, ci = ia - ri * 14;
    int rj = j / 14, cj = j - rj * 14;
    int dr = ri > rj ? ri - rj : rj - ri;
    int dc = ci > cj ? ci - cj : cj - ci;
    int off = dr * 14 + dc;
    float outv[8];
#pragma unroll
    for (int g = 0; g < 8; ++g) {
      float s = ab2[g * NPIX + off];
#pragma unroll
      for (int h = 0; h < 8; ++h) s += c1[g * 8 + h] * sv[h];
      outv[g] = s;
    }
#pragma unroll
    for (int g = 0; g < 8; ++g)
      *(bf16*)(smem + saddr(g, i, j)) = f2b(outv[g]);
  }
  __syncthreads();
  // ---- pass B: softmax over j (4 threads per (g,i) row), zero pad cols ----
  {
    int row = tid >> 2, part = tid & 3;  // 128 rows = 8 heads x 16
    int g = row >> 4, i = row & 15;
    int jb = part * 49, je = jb + 49;
    float m = -1e30f;
    for (int j = jb; j < je; ++j)
      m = fmaxf(m, b2f(*(const bf16*)(smem + saddr(g, i, j))));
    m = fmaxf(m, __shfl_xor(m, 1));
    m = fmaxf(m, __shfl_xor(m, 2));
    float s = 0.f;
    for (int j = jb; j < je; ++j)
      s += __expf(b2f(*(const bf16*)(smem + saddr(g, i, j))) - m);
    s += __shfl_xor(s, 1);
    s += __shfl_xor(s, 2);
    float inv = 1.f / s;
    for (int j = jb; j < je; ++j) {
      bf16* p = (bf16*)(smem + saddr(g, i, j));
      *p = f2b(__expf(b2f(*p) - m) * inv);
    }
    if (part == 3)
      for (int j = NPIX; j < VP; ++j)
        *(bf16*)(smem + saddr(g, i, j)) = f2b(0.f);
  }
  __syncthreads();
  // ---- pass C: talking-head-2 mix ----
  for (int pos = tid; pos < 16 * NPIX; pos += 512) {
    int i = pos / NPIX, j = pos - i * NPIX;
    float pv[8];
#pragma unroll
    for (int g = 0; g < 8; ++g) pv[g] = b2f(*(const bf16*)(smem + saddr(g, i, j)));
#pragma unroll
    for (int g2 = 0; g2 < 8; ++g2) {
      float s = 0.f;
#pragma unroll
      for (int g = 0; g < 8; ++g) s += c2[g2 * 8 + g] * pv[g];
      *(bf16*)(smem + saddr(g2, i, j)) = f2b(s);
    }
  }
  __syncthreads();
  // ---- PV: O_g = P_g @ V_g^T, +th2b*colsum(v) +vl, relu, store transposed ----
  {
    int g = wave;
    f32x4 oacc[8];
#pragma unroll
    for (int dt = 0; dt < 8; ++dt)
#pragma unroll
      for (int r = 0; r < 4; ++r) oacc[dt][r] = 0.f;
    const bf16* vbase = v4 + ((size_t)b * DH + g * DHEAD) * VP;
    for (int ks = 0; ks < 7; ++ks) {
      short8 pa = *(const short8*)(smem + saddr(g, il, ks * 32 + kh * 8));
#pragma unroll
      for (int dt = 0; dt < 8; ++dt) {
        short8 bv = *(const short8*)(vbase + (size_t)(dt * 16 + il) * VP + ks * 32 + kh * 8);
        oacc[dt] = __builtin_amdgcn_mfma_f32_16x16x32_bf16(pa, bv, oacc[dt], 0, 0, 0);
      }
    }
    float t2b = th2b[g];
#pragma unroll
    for (int dt = 0; dt < 8; ++dt) {
      int ch = g * DHEAD + dt * 16 + il;
      float csv = vcs[b * DH + ch] * t2b;
#pragma unroll
      for (int r = 0; r < 4; ++r) {
        int n = i0 + kh * 4 + r;
        if (n < NPIX) {
          float val = oacc[dt][r] + csv + b2f(vl[((size_t)b * DH + ch) * NPIX + n]);
          OT[((size_t)b * NPAD + n) * DH + ch] = f2b(fmaxf(val, 0.f));
        } else {
          OT[((size_t)b * NPAD + n) * DH + ch] = f2b(0.f);
        }
      }
    }
  }
}

extern "C" void kernel_launch(void* const* d_in, const int* in_sizes, int n_in,
                              void* d_out, int out_size, void* d_ws, size_t ws_size,
                              hipStream_t stream) {
  const float* x    = (const float*)d_in[0];
  const float* qw   = (const float*)d_in[1];
  const float* qb   = (const float*)d_in[2];
  const float* q_s  = (const float*)d_in[3];
  const float* q_t  = (const float*)d_in[4];
  const float* kw   = (const float*)d_in[5];
  const float* kb   = (const float*)d_in[6];
  const float* k_s  = (const float*)d_in[7];
  const float* k_t  = (const float*)d_in[8];
  const float* vw   = (const float*)d_in[9];
  const float* vb   = (const float*)d_in[10];
  const float* v_s  = (const float*)d_in[11];
  const float* v_t  = (const float*)d_in[12];
  const float* lvw  = (const float*)d_in[13];
  const float* lvb  = (const float*)d_in[14];
  const float* lv_s = (const float*)d_in[15];
  const float* lv_t = (const float*)d_in[16];
  const float* th1w = (const float*)d_in[17];
  const float* th1b = (const float*)d_in[18];
  const float* th2w = (const float*)d_in[19];
  const float* th2b = (const float*)d_in[20];
  const float* ab   = (const float*)d_in[21];
  const float* pw   = (const float*)d_in[22];
  const float* pb   = (const float*)d_in[23];
  const float* p_s  = (const float*)d_in[24];
  const float* p_t  = (const float*)d_in[25];

  char* ws = (char*)d_ws;
  size_t off = 0;
  auto alloc = [&](size_t bytes) {
    char* p = ws + off;
    off += (bytes + 255) & ~(size_t)255;
    return p;
  };
  // region0: XT (B,208,384 bf16) aliased with OT (B,208,1024 bf16)
  char* region0 = alloc((size_t)NB * NPAD * DH * 2);
  bf16* XT  = (bf16*)region0;
  bf16* OT  = (bf16*)region0;
  bf16* qfb = (bf16*)alloc((size_t)NB * NH * QROWS * KD * 2);
  bf16* kfb = (bf16*)alloc((size_t)NB * NH * QROWS * KD * 2);
  bf16* v4  = (bf16*)alloc((size_t)NB * DH * VP * 2);
  bf16* vlb = (bf16*)alloc((size_t)NB * DH * NPIX * 2);
  float* vcs = (float*)alloc((size_t)NB * DH * 4);
  bf16* wf  = (bf16*)alloc((size_t)1536 * DIM * 2);  // fused Q|K|V weights
  bf16* wpb = (bf16*)alloc((size_t)DIM * DH * 2);
  (void)ws_size; (void)in_sizes; (void)n_in; (void)out_size;

  k_cvt<<<dim3((256 * DIM + 255) / 256), 256, 0, stream>>>(qw, wf, 256 * DIM);
  k_cvt<<<dim3((256 * DIM + 255) / 256), 256, 0, stream>>>(kw, wf + 256 * DIM, 256 * DIM);
  k_cvt<<<dim3((DH * DIM + 255) / 256), 256, 0, stream>>>(vw, wf + 512 * DIM, DH * DIM);
  k_cvt<<<dim3((DIM * DH + 255) / 256), 256, 0, stream>>>(pw, wpb, DIM * DH);
  k_xt<<<dim3(12, 7, NB), 256, 0, stream>>>(x, XT);
  k_qkv2<<<dim3(2496), 256, 0, stream>>>(wf, XT, qb, q_s, q_t, kb, k_s, k_t,
                                         vb, v_s, v_t, qfb, kfb, v4);
  k_vpad<<<dim3((NB * DH * 16 + 255) / 256), 256, 0, stream>>>(v4);
  k_dw<<<dim3(NB * 256), 256, 0, stream>>>(v4, lvw, lvb, lv_s, lv_t, vlb);
  k_vcs<<<dim3(NB, 16), 256, 0, stream>>>(v4, vcs);
  k_att<<<dim3(13, NB), 512, 0, stream>>>(qfb, kfb, v4, vlb, vcs,
                                          th1w, th1b, th2w, th2b, ab, OT);
  k_p2<<<dim3(624), 256, 0, stream>>>(wpb, OT, pb, p_s, p_t, (float*)d_out);
}

// Round 5
// 447.442 us; speedup vs baseline: 1.7673x; 1.1148x over previous
//
#include <hip/hip_runtime.h>
#include <hip/hip_bf16.h>
#include <stdint.h>

typedef __hip_bfloat16 bf16;
typedef short short8 __attribute__((ext_vector_type(8)));
typedef float f32x4 __attribute__((ext_vector_type(4)));

#define NB 128
#define NPIX 196      // 14*14
#define NPAD 208      // 13*16
#define VP 224        // v4 row pitch (7*32 for PV k-steps), cols [208,224) zeroed
#define QROWS 208     // q/k rows allocated+written (pad rows zeroed)
#define NH 8
#define KD 32
#define DHEAD 128
#define DH 1024
#define DIM 384
#define NROWS (NB * NPAD)   // 26624 fused pixel-rows
#define SCALE 0.17677669529663687f

__device__ __forceinline__ float b2f(bf16 v) { return __bfloat162float(v); }
__device__ __forceinline__ bf16 f2b(float f) { return __float2bfloat16(f); }

// CK-style global->LDS 16B async copy
__device__ __forceinline__ void gll16(const void* g, void* l) {
  auto gp = reinterpret_cast<const uint32_t __attribute__((address_space(1)))*>(
      reinterpret_cast<uintptr_t>(g));
  auto lp = reinterpret_cast<uint32_t __attribute__((address_space(3)))*>(
      reinterpret_cast<uintptr_t>(l));
  __builtin_amdgcn_global_load_lds(gp, lp, 16, 0, 0);
}

// ---------- fp32 -> bf16 weight conversion ----------
__global__ __launch_bounds__(256) void k_cvt(const float* __restrict__ src,
                                             bf16* __restrict__ dst, int n) {
  int i = blockIdx.x * 256 + threadIdx.x;
  if (i < n) dst[i] = f2b(src[i]);
}

// ---------- transpose x (B,384,196) fp32 -> XT (B,208,384) bf16, rows >=196 zeroed ----------
__global__ __launch_bounds__(256) void k_xt(const float* __restrict__ x,
                                            bf16* __restrict__ XT) {
  __shared__ bf16 tile[32][33];
  int ct = blockIdx.x, nt = blockIdx.y, b = blockIdx.z;
  int c0 = ct * 32, n0 = nt * 32;
  int tc = threadIdx.x >> 5, tn = threadIdx.x & 31;
#pragma unroll
  for (int r = 0; r < 4; ++r) {
    int c = tc + r * 8;
    int n = n0 + tn;
    float v = 0.f;
    if (n < NPIX) v = x[((size_t)b * DIM + c0 + c) * NPIX + n];
    tile[c][tn] = f2b(v);
  }
  __syncthreads();
#pragma unroll
  for (int r = 0; r < 4; ++r) {
    int n = n0 + tc + r * 8;
    if (n < NPAD) XT[((size_t)b * NPAD + n) * DIM + c0 + tn] = tile[tn][tc + r * 8];
  }
}

// ---------- fused QKV projection: LDS-staged 128x128 tile GEMM ----------
// A = Wf [1536][384] bf16, B = XT [26624][384] bf16.
__global__ __launch_bounds__(256, 2) void k_qkv2(
    const bf16* __restrict__ Wf, const bf16* __restrict__ XT,
    const float* __restrict__ qb, const float* __restrict__ qs, const float* __restrict__ qt,
    const float* __restrict__ kb, const float* __restrict__ ks, const float* __restrict__ kt,
    const float* __restrict__ vb, const float* __restrict__ vs, const float* __restrict__ vt,
    bf16* __restrict__ qf, bf16* __restrict__ kf, bf16* __restrict__ v4) {
  __shared__ __align__(16) char lds[2][32768];  // [buf][A 16KB | B 16KB]
  const int NWG = 12 * 208;  // 2496, %8==0
  int id = blockIdx.x;
  int id2 = (id & 7) * (NWG >> 3) + (id >> 3);  // XCD-contiguous
  int mt = id2 % 12, nt = id2 / 12;
  int m0 = mt * 128, n0 = nt * 128;
  int tid = threadIdx.x, lane = tid & 63;
  int wv = tid >> 6, wm = wv >> 1, wn = wv & 1;

  f32x4 acc[4][4];
#pragma unroll
  for (int mi = 0; mi < 4; ++mi)
#pragma unroll
    for (int ni = 0; ni < 4; ++ni)
#pragma unroll
      for (int r = 0; r < 4; ++r) acc[mi][ni][r] = 0.f;

  auto stage = [&](int buf, int t) {
    int k0 = t * 64;
#pragma unroll
    for (int j = 0; j < 4; ++j) {
      int gi = tid + j * 256;
      int row = gi >> 3, g = gi & 7;
      int sk = k0 + ((g ^ (row & 7)) << 3);
      gll16(Wf + (size_t)(m0 + row) * DIM + sk, &lds[buf][gi * 16]);
      gll16(XT + (size_t)(n0 + row) * DIM + sk, &lds[buf][16384 + gi * 16]);
    }
  };
  auto compute = [&](int buf) {
    const char* Ab = lds[buf];
    const char* Bb = lds[buf] + 16384;
    int kq = lane >> 4, il = lane & 15;
#pragma unroll
    for (int ksb = 0; ksb < 2; ++ksb) {
      int G = ksb * 4 + kq;
      short8 af[4], bfr[4];
#pragma unroll
      for (int mi = 0; mi < 4; ++mi) {
        int row = wm * 64 + mi * 16 + il;
        af[mi] = *(const short8*)(Ab + row * 128 + ((G ^ (row & 7)) << 4));
      }
#pragma unroll
      for (int ni = 0; ni < 4; ++ni) {
        int row = wn * 64 + ni * 16 + il;
        bfr[ni] = *(const short8*)(Bb + row * 128 + ((G ^ (row & 7)) << 4));
      }
#pragma unroll
      for (int mi = 0; mi < 4; ++mi)
#pragma unroll
        for (int ni = 0; ni < 4; ++ni)
          acc[mi][ni] = __builtin_amdgcn_mfma_f32_16x16x32_bf16(af[mi], bfr[ni], acc[mi][ni], 0, 0, 0);
    }
  };

  stage(0, 0);
  __syncthreads();
  for (int t = 0; t < 6; ++t) {
    if (t < 5) stage((t + 1) & 1, t + 1);
    compute(t & 1);
    __syncthreads();
  }

  int cq = lane >> 4, cn = lane & 15;
#pragma unroll
  for (int mi = 0; mi < 4; ++mi) {
    int mbase = m0 + wm * 64 + mi * 16;
    const float *bp, *sp, *tp;
    int segbase, segid;
    if (mbase < 256)      { bp = qb; sp = qs; tp = qt; segbase = 0;   segid = 0; }
    else if (mbase < 512) { bp = kb; sp = ks; tp = kt; segbase = 256; segid = 1; }
    else                  { bp = vb; sp = vs; tp = vt; segbase = 512; segid = 2; }
#pragma unroll
    for (int r = 0; r < 4; ++r) {
      int ms = mbase - segbase + cq * 4 + r;
      float bi = bp[ms], sc = sp[ms], tt = tp[ms];
#pragma unroll
      for (int ni = 0; ni < 4; ++ni) {
        int n = n0 + wn * 64 + ni * 16 + cn;
        int b = n / NPAD;
        int nn = n - b * NPAD;
        float y = (acc[mi][ni][r] + bi) * sc + tt;
        y = (nn < NPIX) ? y : 0.f;
        if (segid == 2) {
          v4[((size_t)b * DH + ms) * VP + nn] = f2b(y);
        } else {
          bf16* dst = segid ? kf : qf;
          dst[(((size_t)b * NH + (ms >> 5)) * QROWS + nn) * KD + (ms & 31)] = f2b(y);
        }
      }
    }
  }
}

// ---------- zero v4 pad cols [208,224) ----------
__global__ __launch_bounds__(256) void k_vpad(bf16* __restrict__ v4) {
  int i = blockIdx.x * 256 + threadIdx.x;
  int tot = NB * DH * 16;
  if (i < tot) {
    int row = i >> 4, c = i & 15;
    v4[(size_t)row * VP + 208 + c] = f2b(0.f);
  }
}

// ---------- final projection: LDS-staged 128x128 tile GEMM, fp32 out ----------
// A = Pw [384][1024] bf16, B = OT [26624][1024] bf16.
__global__ __launch_bounds__(256, 2) void k_p2(
    const bf16* __restrict__ Pw, const bf16* __restrict__ OT,
    const float* __restrict__ pb, const float* __restrict__ ps, const float* __restrict__ pt,
    float* __restrict__ out) {
  __shared__ __align__(16) char lds[2][32768];
  const int NWG = 3 * 208;  // 624, %8==0
  int id = blockIdx.x;
  int id2 = (id & 7) * (NWG >> 3) + (id >> 3);
  int mt = id2 % 3, nt = id2 / 3;
  int m0 = mt * 128, n0 = nt * 128;
  int tid = threadIdx.x, lane = tid & 63;
  int wv = tid >> 6, wm = wv >> 1, wn = wv & 1;

  f32x4 acc[4][4];
#pragma unroll
  for (int mi = 0; mi < 4; ++mi)
#pragma unroll
    for (int ni = 0; ni < 4; ++ni)
#pragma unroll
      for (int r = 0; r < 4; ++r) acc[mi][ni][r] = 0.f;

  auto stage = [&](int buf, int t) {
    int k0 = t * 64;
#pragma unroll
    for (int j = 0; j < 4; ++j) {
      int gi = tid + j * 256;
      int row = gi >> 3, g = gi & 7;
      int sk = k0 + ((g ^ (row & 7)) << 3);
      gll16(Pw + (size_t)(m0 + row) * DH + sk, &lds[buf][gi * 16]);
      gll16(OT + (size_t)(n0 + row) * DH + sk, &lds[buf][16384 + gi * 16]);
    }
  };
  auto compute = [&](int buf) {
    const char* Ab = lds[buf];
    const char* Bb = lds[buf] + 16384;
    int kq = lane >> 4, il = lane & 15;
#pragma unroll
    for (int ksb = 0; ksb < 2; ++ksb) {
      int G = ksb * 4 + kq;
      short8 af[4], bfr[4];
#pragma unroll
      for (int mi = 0; mi < 4; ++mi) {
        int row = wm * 64 + mi * 16 + il;
        af[mi] = *(const short8*)(Ab + row * 128 + ((G ^ (row & 7)) << 4));
      }
#pragma unroll
      for (int ni = 0; ni < 4; ++ni) {
        int row = wn * 64 + ni * 16 + il;
        bfr[ni] = *(const short8*)(Bb + row * 128 + ((G ^ (row & 7)) << 4));
      }
#pragma unroll
      for (int mi = 0; mi < 4; ++mi)
#pragma unroll
        for (int ni = 0; ni < 4; ++ni)
          acc[mi][ni] = __builtin_amdgcn_mfma_f32_16x16x32_bf16(af[mi], bfr[ni], acc[mi][ni], 0, 0, 0);
    }
  };

  stage(0, 0);
  __syncthreads();
  for (int t = 0; t < 16; ++t) {
    if (t < 15) stage((t + 1) & 1, t + 1);
    compute(t & 1);
    __syncthreads();
  }

  int cq = lane >> 4, cn = lane & 15;
#pragma unroll
  for (int mi = 0; mi < 4; ++mi) {
#pragma unroll
    for (int r = 0; r < 4; ++r) {
      int m = m0 + wm * 64 + mi * 16 + cq * 4 + r;
      float bi = pb[m], sc = ps[m], tt = pt[m];
#pragma unroll
      for (int ni = 0; ni < 4; ++ni) {
        int n = n0 + wn * 64 + ni * 16 + cn;
        int b = n / NPAD;
        int nn = n - b * NPAD;
        if (nn < NPIX)
          out[((size_t)b * DIM + m) * NPIX + nn] = (acc[mi][ni][r] + bi) * sc + tt;
      }
    }
  }
}

// ---------- depthwise 3x3 + BN ----------
__global__ __launch_bounds__(256) void k_dw(
    const bf16* __restrict__ v4, const float* __restrict__ lvw,
    const float* __restrict__ lvb, const float* __restrict__ lvs,
    const float* __restrict__ lvt, bf16* __restrict__ vl) {
  int blk = blockIdx.x;
  int b = blk >> 8, cg = blk & 255;
  int lc = threadIdx.x >> 6, px = threadIdx.x & 63;
  int ch = cg * 4 + lc;
  const bf16* src = v4 + ((size_t)b * DH + ch) * VP;
  float w[9];
#pragma unroll
  for (int i = 0; i < 9; ++i) w[i] = lvw[ch * 9 + i];
  float bb = lvb[ch], ss = lvs[ch], tt = lvt[ch];
  bf16* dst = vl + ((size_t)b * DH + ch) * NPIX;
  for (int p = px; p < NPIX; p += 64) {
    int ri = p / 14, ci = p - ri * 14;
    float s = 0.f;
#pragma unroll
    for (int dy = -1; dy <= 1; ++dy)
#pragma unroll
      for (int dx = -1; dx <= 1; ++dx) {
        int rr = ri + dy, cc = ci + dx;
        if (rr >= 0 && rr < 14 && cc >= 0 && cc < 14)
          s += w[(dy + 1) * 3 + dx + 1] * b2f(src[rr * 14 + cc]);
      }
    dst[p] = f2b((s + bb) * ss + tt);
  }
}

// ---------- per-channel column sums of v (for the th2b term) ----------
__global__ __launch_bounds__(256) void k_vcs(const bf16* __restrict__ v4,
                                             float* __restrict__ vcs) {
  int b = blockIdx.x, g = blockIdx.y;
  int ch = g * 64 + (threadIdx.x >> 2);
  int part = threadIdx.x & 3;
  const bf16* src = v4 + ((size_t)b * DH + ch) * VP + part * 49;
  float s = 0.f;
  for (int j = 0; j < 49; ++j) s += b2f(src[j]);
  s += __shfl_xor(s, 1);
  s += __shfl_xor(s, 2);
  if (part == 0) vcs[b * DH + ch] = s;
}

// ---------- attention ----------
// S: bf16 [8 heads][16 rows][224 cols], row rotate-swizzled. 57344 B static LDS.
#define SROW 448  // bytes per S row
__device__ __forceinline__ int saddr(int g, int i, int j) {
  int r = j * 2 + ((i & 7) << 4);
  if (r >= SROW) r -= SROW;
  return (g * 16 + i) * SROW + r;
}

__global__ __launch_bounds__(512, 2) void k_att(
    const bf16* __restrict__ qf, const bf16* __restrict__ kf,
    const bf16* __restrict__ v4, const bf16* __restrict__ vl,
    const float* __restrict__ vcs,
    const float* __restrict__ th1w, const float* __restrict__ th1b,
    const float* __restrict__ th2w, const float* __restrict__ th2b,
    const float* __restrict__ ab, bf16* __restrict__ OT) {
  __shared__ __align__(16) char smem[NH * 16 * SROW];  // 57344 B
  __shared__ float ab2[NH * NPIX];                     // 6272 B
  __shared__ float c1[64];
  __shared__ float c2[64];
  // batch->XCD affinity: all 13 Q-tiles of a batch share one XCD's L2,
  // so K/V re-reads (13x per batch) hit L2 instead of HBM.
  int id = blockIdx.x;            // 1664 linear
  int xcd = id & 7;
  int rest = id >> 3;             // [0,208)
  int qt = rest % 13;
  int b = (rest / 13) * 8 + xcd;  // [0,128), b%8 == xcd
  int i0 = qt * 16;
  int tid = threadIdx.x;
  int wave = tid >> 6, lane = tid & 63;
  int il = lane & 15, kh = lane >> 4;

  if (tid < 64) {
    c1[tid] = th1w[tid] * SCALE;
    c2[tid] = th2w[tid];
  }
  for (int pos = tid; pos < NH * NPIX; pos += 512) {
    int g = pos / NPIX, off = pos - g * NPIX;
    float s = th1b[g];
#pragma unroll
    for (int h = 0; h < 8; ++h)
      s += th1w[g * 8 + h] * ab[h * NPIX + off];
    ab2[pos] = s;
  }
  // ---- QK^T, head = wave; 16 q-rows x 208 k-rows, raw qk -> S (bf16) ----
  {
    const bf16* qp = qf + ((size_t)b * NH + wave) * QROWS * KD;
    const bf16* kp = kf + ((size_t)b * NH + wave) * QROWS * KD;
    short8 a = *(const short8*)(qp + (i0 + il) * KD + kh * 8);
    for (int jt = 0; jt < 13; ++jt) {
      short8 bb = *(const short8*)(kp + (jt * 16 + il) * KD + kh * 8);
      f32x4 acc = {0.f, 0.f, 0.f, 0.f};
      acc = __builtin_amdgcn_mfma_f32_16x16x32_bf16(a, bb, acc, 0, 0, 0);
      int j = jt * 16 + il;
#pragma unroll
      for (int r = 0; r < 4; ++r)
        *(bf16*)(smem + saddr(wave, kh * 4 + r, j)) = f2b(acc[r]);
    }
  }
  __syncthreads();
  // ---- pass A: talking-head-1 mix (with SCALE) + relative-position bias ----
  for (int pos = tid; pos < 16 * NPIX; pos += 512) {
    int i = pos / NPIX, j = pos - i * NPIX;
    float sv[8];
#pragma unroll
    for (int h = 0; h < 8; ++h) sv[h] = b2f(*(const bf16*)(smem + saddr(h, i, j)));
    int ia = i0 + i; if (ia > 195) ia = 195;
    int ri = ia / 14, ci = ia - ri * 14;
    int rj = j / 14, cj = j - rj * 14;
    int dr = ri > rj ? ri - rj : rj - ri;
    int dc = ci > cj ? ci - cj : cj - ci;
    int off = dr * 14 + dc;
    float outv[8];
#pragma unroll
    for (int g = 0; g < 8; ++g) {
      float s = ab2[g * NPIX + off];
#pragma unroll
      for (int h = 0; h < 8; ++h) s += c1[g * 8 + h] * sv[h];
      outv[g] = s;
    }
#pragma unroll
    for (int g = 0; g < 8; ++g)
      *(bf16*)(smem + saddr(g, i, j)) = f2b(outv[g]);
  }
  __syncthreads();
  // ---- pass B: softmax over j (4 threads per (g,i) row), zero pad cols ----
  {
    int row = tid >> 2, part = tid & 3;  // 128 rows = 8 heads x 16
    int g = row >> 4, i = row & 15;
    int jb = part * 49, je = jb + 49;
    float m = -1e30f;
    for (int j = jb; j < je; ++j)
      m = fmaxf(m, b2f(*(const bf16*)(smem + saddr(g, i, j))));
    m = fmaxf(m, __shfl_xor(m, 1));
    m = fmaxf(m, __shfl_xor(m, 2));
    float s = 0.f;
    for (int j = jb; j < je; ++j)
      s += __expf(b2f(*(const bf16*)(smem + saddr(g, i, j))) - m);
    s += __shfl_xor(s, 1);
    s += __shfl_xor(s, 2);
    float inv = 1.f / s;
    for (int j = jb; j < je; ++j) {
      bf16* p = (bf16*)(smem + saddr(g, i, j));
      *p = f2b(__expf(b2f(*p) - m) * inv);
    }
    if (part == 3)
      for (int j = NPIX; j < VP; ++j)
        *(bf16*)(smem + saddr(g, i, j)) = f2b(0.f);
  }
  __syncthreads();
  // ---- pass C: talking-head-2 mix ----
  for (int pos = tid; pos < 16 * NPIX; pos += 512) {
    int i = pos / NPIX, j = pos - i * NPIX;
    float pv[8];
#pragma unroll
    for (int g = 0; g < 8; ++g) pv[g] = b2f(*(const bf16*)(smem + saddr(g, i, j)));
#pragma unroll
    for (int g2 = 0; g2 < 8; ++g2) {
      float s = 0.f;
#pragma unroll
      for (int g = 0; g < 8; ++g) s += c2[g2 * 8 + g] * pv[g];
      *(bf16*)(smem + saddr(g2, i, j)) = f2b(s);
    }
  }
  __syncthreads();
  // ---- PV: O_g = P_g @ V_g^T, +th2b*colsum(v) +vl, relu, store transposed ----
  {
    int g = wave;
    f32x4 oacc[8];
#pragma unroll
    for (int dt = 0; dt < 8; ++dt)
#pragma unroll
      for (int r = 0; r < 4; ++r) oacc[dt][r] = 0.f;
    const bf16* vbase = v4 + ((size_t)b * DH + g * DHEAD) * VP;
    for (int ks = 0; ks < 7; ++ks) {
      short8 pa = *(const short8*)(smem + saddr(g, il, ks * 32 + kh * 8));
#pragma unroll
      for (int dt = 0; dt < 8; ++dt) {
        short8 bv = *(const short8*)(vbase + (size_t)(dt * 16 + il) * VP + ks * 32 + kh * 8);
        oacc[dt] = __builtin_amdgcn_mfma_f32_16x16x32_bf16(pa, bv, oacc[dt], 0, 0, 0);
      }
    }
    float t2b = th2b[g];
#pragma unroll
    for (int dt = 0; dt < 8; ++dt) {
      int ch = g * DHEAD + dt * 16 + il;
      float csv = vcs[b * DH + ch] * t2b;
#pragma unroll
      for (int r = 0; r < 4; ++r) {
        int n = i0 + kh * 4 + r;
        if (n < NPIX) {
          float val = oacc[dt][r] + csv + b2f(vl[((size_t)b * DH + ch) * NPIX + n]);
          OT[((size_t)b * NPAD + n) * DH + ch] = f2b(fmaxf(val, 0.f));
        } else {
          OT[((size_t)b * NPAD + n) * DH + ch] = f2b(0.f);
        }
      }
    }
  }
}

extern "C" void kernel_launch(void* const* d_in, const int* in_sizes, int n_in,
                              void* d_out, int out_size, void* d_ws, size_t ws_size,
                              hipStream_t stream) {
  const float* x    = (const float*)d_in[0];
  const float* qw   = (const float*)d_in[1];
  const float* qb   = (const float*)d_in[2];
  const float* q_s  = (const float*)d_in[3];
  const float* q_t  = (const float*)d_in[4];
  const float* kw   = (const float*)d_in[5];
  const float* kb   = (const float*)d_in[6];
  const float* k_s  = (const float*)d_in[7];
  const float* k_t  = (const float*)d_in[8];
  const float* vw   = (const float*)d_in[9];
  const float* vb   = (const float*)d_in[10];
  const float* v_s  = (const float*)d_in[11];
  const float* v_t  = (const float*)d_in[12];
  const float* lvw  = (const float*)d_in[13];
  const float* lvb  = (const float*)d_in[14];
  const float* lv_s = (const float*)d_in[15];
  const float* lv_t = (const float*)d_in[16];
  const float* th1w = (const float*)d_in[17];
  const float* th1b = (const float*)d_in[18];
  const float* th2w = (const float*)d_in[19];
  const float* th2b = (const float*)d_in[20];
  const float* ab   = (const float*)d_in[21];
  const float* pw   = (const float*)d_in[22];
  const float* pb   = (const float*)d_in[23];
  const float* p_s  = (const float*)d_in[24];
  const float* p_t  = (const float*)d_in[25];

  char* ws = (char*)d_ws;
  size_t off = 0;
  auto alloc = [&](size_t bytes) {
    char* p = ws + off;
    off += (bytes + 255) & ~(size_t)255;
    return p;
  };
  // region0: XT (B,208,384 bf16) aliased with OT (B,208,1024 bf16)
  char* region0 = alloc((size_t)NB * NPAD * DH * 2);
  bf16* XT  = (bf16*)region0;
  bf16* OT  = (bf16*)region0;
  bf16* qfb = (bf16*)alloc((size_t)NB * NH * QROWS * KD * 2);
  bf16* kfb = (bf16*)alloc((size_t)NB * NH * QROWS * KD * 2);
  bf16* v4  = (bf16*)alloc((size_t)NB * DH * VP * 2);
  bf16* vlb = (bf16*)alloc((size_t)NB * DH * NPIX * 2);
  float* vcs = (float*)alloc((size_t)NB * DH * 4);
  bf16* wf  = (bf16*)alloc((size_t)1536 * DIM * 2);  // fused Q|K|V weights
  bf16* wpb = (bf16*)alloc((size_t)DIM * DH * 2);
  (void)ws_size; (void)in_sizes; (void)n_in; (void)out_size;

  k_cvt<<<dim3((256 * DIM + 255) / 256), 256, 0, stream>>>(qw, wf, 256 * DIM);
  k_cvt<<<dim3((256 * DIM + 255) / 256), 256, 0, stream>>>(kw, wf + 256 * DIM, 256 * DIM);
  k_cvt<<<dim3((DH * DIM + 255) / 256), 256, 0, stream>>>(vw, wf + 512 * DIM, DH * DIM);
  k_cvt<<<dim3((DIM * DH + 255) / 256), 256, 0, stream>>>(pw, wpb, DIM * DH);
  k_xt<<<dim3(12, 7, NB), 256, 0, stream>>>(x, XT);
  k_qkv2<<<dim3(2496), 256, 0, stream>>>(wf, XT, qb, q_s, q_t, kb, k_s, k_t,
                                         vb, v_s, v_t, qfb, kfb, v4);
  k_vpad<<<dim3((NB * DH * 16 + 255) / 256), 256, 0, stream>>>(v4);
  k_dw<<<dim3(NB * 256), 256, 0, stream>>>(v4, lvw, lvb, lv_s, lv_t, vlb);
  k_vcs<<<dim3(NB, 16), 256, 0, stream>>>(v4, vcs);
  k_att<<<dim3(1664), 512, 0, stream>>>(qfb, kfb, v4, vlb, vcs,
                                        th1w, th1b, th2w, th2b, ab, OT);
  k_p2<<<dim3(624), 256, 0, stream>>>(wpb, OT, pb, p_s, p_t, (float*)d_out);
}